// Round 1
// baseline (191.807 us; speedup 1.0000x reference)
//
#include <hip/hip_runtime.h>
#include <cstdint>

#define BATCH 64
#define NPIX 65536
#define TOPK 16384
#define NBINS 4096
#define NC 2  // histogram copies to cut LDS-atomic contention

// ---------------------------------------------------------------------------
// Kernel 1: per-batch exact top-K threshold via 3-pass bit-radix select.
// Values are uniform [0,1) -> non-negative floats -> uint bit pattern is
// order-monotone. Pass keys: bits[31:20] (12b), bits[19:8] (12b), bits[7:0].
// Also resolves lax.top_k's lowest-index tie-breaking: outputs the largest
// index (cut) such that elements == T with i <= cut are selected.
// ---------------------------------------------------------------------------
__global__ __launch_bounds__(1024) void select_kernel(
    const float* __restrict__ smap,
    uint32_t* __restrict__ tb_out,   // [BATCH] threshold bits
    int* __restrict__ cut_out)       // [BATCH] tie index cutoff (inclusive)
{
    const int b = blockIdx.x;
    const int tid = threadIdx.x;
    const float* tok = smap + (size_t)b * NPIX;

    __shared__ uint32_t hist[NC][NBINS];
    __shared__ uint32_t chunk[64];
    __shared__ uint32_t sh_bin, sh_rem;
    __shared__ int sh_cnt;
    __shared__ int idxbuf[256];

    const int cp = (tid >> 6) & (NC - 1);

    // ---------------- Phase A: key = bits >> 20 ----------------
    for (int i = tid; i < NC * NBINS; i += 1024) (&hist[0][0])[i] = 0u;
    __syncthreads();
    for (int i = tid; i < NPIX; i += 1024) {
        uint32_t bits = __float_as_uint(tok[i]);
        atomicAdd(&hist[cp][bits >> 20], 1u);
    }
    __syncthreads();
    if (tid < 64) {
        uint32_t s = 0;
        for (int j = 0; j < 64; j++) {
            int bin = tid * 64 + j;
            uint32_t t = 0;
            for (int c = 0; c < NC; c++) t += hist[c][bin];
            s += t;
        }
        chunk[tid] = s;
    }
    __syncthreads();
    if (tid == 0) {
        uint32_t need = TOPK, cum = 0;
        int ch = 63;
        for (; ch > 0; ch--) {
            if (cum + chunk[ch] >= need) break;
            cum += chunk[ch];
        }
        int bin = ch * 64 + 63;
        for (; bin > 0; bin--) {
            uint32_t t = 0;
            for (int c = 0; c < NC; c++) t += hist[c][bin];
            if (cum + t >= need) break;
            cum += t;
        }
        sh_bin = (uint32_t)bin;
        sh_rem = need - cum;
    }
    __syncthreads();
    const uint32_t b1 = sh_bin;
    const uint32_t need2 = sh_rem;
    __syncthreads();

    // ---------------- Phase B: filter b1, key = (bits >> 8) & 0xFFF --------
    for (int i = tid; i < NC * NBINS; i += 1024) (&hist[0][0])[i] = 0u;
    __syncthreads();
    for (int i = tid; i < NPIX; i += 1024) {
        uint32_t bits = __float_as_uint(tok[i]);
        if ((bits >> 20) == b1)
            atomicAdd(&hist[cp][(bits >> 8) & 0xFFFu], 1u);
    }
    __syncthreads();
    if (tid < 64) {
        uint32_t s = 0;
        for (int j = 0; j < 64; j++) {
            int bin = tid * 64 + j;
            uint32_t t = 0;
            for (int c = 0; c < NC; c++) t += hist[c][bin];
            s += t;
        }
        chunk[tid] = s;
    }
    __syncthreads();
    if (tid == 0) {
        uint32_t need = need2, cum = 0;
        int ch = 63;
        for (; ch > 0; ch--) {
            if (cum + chunk[ch] >= need) break;
            cum += chunk[ch];
        }
        int bin = ch * 64 + 63;
        for (; bin > 0; bin--) {
            uint32_t t = 0;
            for (int c = 0; c < NC; c++) t += hist[c][bin];
            if (cum + t >= need) break;
            cum += t;
        }
        sh_bin = (uint32_t)bin;
        sh_rem = need - cum;
    }
    __syncthreads();
    const uint32_t b2 = sh_bin;
    const uint32_t need3 = sh_rem;
    __syncthreads();

    // ---------------- Phase C: filter (b1,b2), key = bits & 0xFF ----------
    const uint32_t pfx = (b1 << 12) | b2;
    for (int i = tid; i < 256; i += 1024) hist[0][i] = 0u;
    __syncthreads();
    for (int i = tid; i < NPIX; i += 1024) {
        uint32_t bits = __float_as_uint(tok[i]);
        if ((bits >> 8) == pfx)
            atomicAdd(&hist[0][bits & 0xFFu], 1u);
    }
    __syncthreads();
    if (tid == 0) {
        uint32_t need = need3, cum = 0;
        int bin = 255;
        for (; bin > 0; bin--) {
            uint32_t t = hist[0][bin];
            if (cum + t >= need) break;
            cum += t;
        }
        sh_bin = (uint32_t)bin;
        sh_rem = need - cum;
    }
    __syncthreads();
    const uint32_t Tbits = (pfx << 8) | sh_bin;
    const uint32_t take = sh_rem;   // how many ==T elements to accept (>=1)
    __syncthreads();

    // ---------------- Phase D: tie-break by lowest index ------------------
    if (tid == 0) sh_cnt = 0;
    __syncthreads();
    for (int i = tid; i < NPIX; i += 1024) {
        if (__float_as_uint(tok[i]) == Tbits) {
            int p = atomicAdd(&sh_cnt, 1);
            if (p < 256) idxbuf[p] = i;
        }
    }
    __syncthreads();
    if (tid == 0) {
        int cnt = sh_cnt;
        int cut;
        if (cnt > 256) {
            cut = NPIX;  // pathological mass of exact ties: accept all (within tol)
        } else {
            // insertion sort ascending (cnt is almost always 1-3)
            for (int a = 1; a < cnt; a++) {
                int v = idxbuf[a];
                int j = a - 1;
                while (j >= 0 && idxbuf[j] > v) { idxbuf[j + 1] = idxbuf[j]; j--; }
                idxbuf[j + 1] = v;
            }
            int tk = (int)take;
            if (tk > cnt) tk = cnt;   // defensive; mathematically take <= cnt
            cut = idxbuf[tk - 1];
        }
        tb_out[b] = Tbits;
        cut_out[b] = cut;
    }
}

// ---------------------------------------------------------------------------
// Kernel 2: fused softmax + BCE-sum. Each iteration handles 2 pixels via
// float4 loads of scores/gumbel and a float2 load of the token map.
// ---------------------------------------------------------------------------
__global__ __launch_bounds__(256) void loss_kernel(
    const float4* __restrict__ sc,    // [BATCH*NPIX/2]
    const float4* __restrict__ gn,    // [BATCH*NPIX/2]
    const float2* __restrict__ tokp,  // [BATCH*NPIX/2]
    const uint32_t* __restrict__ tb,
    const int* __restrict__ cut,
    float* __restrict__ out)
{
    const int gid = blockIdx.x * blockDim.x + threadIdx.x;
    const int stride = gridDim.x * blockDim.x;
    const int npairs = BATCH * NPIX / 2;
    float acc = 0.f;

    for (int j = gid; j < npairs; j += stride) {
        float4 s = sc[j];
        float4 g = gn[j];
        float2 tk = tokp[j];
        int idx0 = 2 * j;
        int b = idx0 >> 16;        // NPIX = 65536
        int i0 = idx0 & 0xFFFF;
        uint32_t T = tb[b];
        int c = cut[b];

        {   // element idx0
            float a0 = s.x + g.x, a1 = s.y + g.y;
            float m = fmaxf(a0, a1);
            float e0 = expf(a0 - m), e1 = expf(a1 - m);
            float soft = e0 / (e0 + e1);
            float lp  = fmaxf(logf(soft), -100.f);
            float l1p = fmaxf(logf(1.f - soft), -100.f);
            uint32_t vb = __float_as_uint(tk.x);
            bool t = (vb > T) || (vb == T && i0 <= c);
            acc += t ? lp : l1p;
        }
        {   // element idx0 + 1
            float a0 = s.z + g.z, a1 = s.w + g.w;
            float m = fmaxf(a0, a1);
            float e0 = expf(a0 - m), e1 = expf(a1 - m);
            float soft = e0 / (e0 + e1);
            float lp  = fmaxf(logf(soft), -100.f);
            float l1p = fmaxf(logf(1.f - soft), -100.f);
            uint32_t vb = __float_as_uint(tk.y);
            bool t = (vb > T) || (vb == T && (i0 + 1) <= c);
            acc += t ? lp : l1p;
        }
    }

    // wave64 reduce, then cross-wave via LDS, one atomic per block
    __shared__ float wsum[4];
    float v = acc;
    #pragma unroll
    for (int off = 32; off > 0; off >>= 1) v += __shfl_down(v, off, 64);
    if ((threadIdx.x & 63) == 0) wsum[threadIdx.x >> 6] = v;
    __syncthreads();
    if (threadIdx.x == 0) {
        float sblk = wsum[0] + wsum[1] + wsum[2] + wsum[3];
        atomicAdd(out, -sblk);
    }
}

extern "C" void kernel_launch(void* const* d_in, const int* in_sizes, int n_in,
                              void* d_out, int out_size, void* d_ws, size_t ws_size,
                              hipStream_t stream) {
    const float* scores = (const float*)d_in[0];   // [B, N, 2]
    const float* smap   = (const float*)d_in[1];   // [B, 1, H, W] == [B, N]
    const float* gumbel = (const float*)d_in[2];   // [B, N, 2]
    float* out = (float*)d_out;

    uint32_t* tb  = (uint32_t*)d_ws;                       // [BATCH]
    int*      cut = (int*)((uint32_t*)d_ws + BATCH);       // [BATCH]

    hipMemsetAsync(out, 0, sizeof(float), stream);

    select_kernel<<<BATCH, 1024, 0, stream>>>(smap, tb, cut);

    loss_kernel<<<2048, 256, 0, stream>>>(
        (const float4*)scores, (const float4*)gumbel, (const float2*)smap,
        tb, cut, out);
}